// Round 19
// baseline (110.475 us; speedup 1.0000x reference)
//
#include <hip/hip_runtime.h>
#include <hip/hip_bf16.h>

#define NPAIR 4096
#define DIM   768            // fp8: 768 bytes per row
#define N2    8192
#define BM    128            // block rows (4 waves as 2x2, each 64x64)
#define BNB   128            // block cols per col-block
#define KBLK  64             // K tile bytes; dbuf = 32KB total
#define KITER (DIM / KBLK)   // 12
#define NSTRIP 16            // grid.y
#define CPB   ((N2 / BNB) / NSTRIP)    // 4 col-blocks per strip
#define NBI   (N2 / BM)      // 64
#define TOT   (CPB * KITER)  // 48 K-tile iterations per block
#define SC1   0x7F7F7F7F     // packed E8M0 scales: all 1.0

constexpr float INV_T = 1.0f / 0.07f;  // also the fixed softmax max M

typedef float f32x16 __attribute__((ext_vector_type(16)));
typedef int   i32x8  __attribute__((ext_vector_type(8)));
#define AS1 __attribute__((address_space(1)))
#define AS3 __attribute__((address_space(3)))

// ---------------- normalize: one wave per row, fp32 in -> fp8 e4m3 out ------
__global__ void knorm(const float* __restrict__ z1, const float* __restrict__ z2,
                      unsigned char* __restrict__ zq) {
    const int row  = blockIdx.x * 4 + (threadIdx.x >> 6);
    const int lane = threadIdx.x & 63;
    const float* src = (row < NPAIR) ? (z1 + (size_t)row * DIM)
                                     : (z2 + (size_t)(row - NPAIR) * DIM);
    float4 v[3];
    float ss = 0.f;
#pragma unroll
    for (int i = 0; i < 3; ++i) {
        v[i] = reinterpret_cast<const float4*>(src)[lane + 64 * i];
        ss += v[i].x * v[i].x + v[i].y * v[i].y + v[i].z * v[i].z + v[i].w * v[i].w;
    }
#pragma unroll
    for (int off = 32; off; off >>= 1) ss += __shfl_xor(ss, off);
    const float scale = 1.0f / fmaxf(sqrtf(ss), 1e-12f);
    unsigned int* dst = reinterpret_cast<unsigned int*>(zq + (size_t)row * DIM);
#pragma unroll
    for (int i = 0; i < 3; ++i) {
        unsigned int u = 0;
        u = __builtin_amdgcn_cvt_pk_fp8_f32(v[i].x * scale, v[i].y * scale, u, false);
        u = __builtin_amdgcn_cvt_pk_fp8_f32(v[i].z * scale, v[i].w * scale, u, true);
        dst[lane + 64 * i] = u;
    }
}

// ---------------- positive-pair dots from fp8 (consistent with klse) --------
__global__ void kpos(const unsigned char* __restrict__ zq, float* __restrict__ pos) {
    const int pair = blockIdx.x * 4 + (threadIdx.x >> 6);
    const int lane = threadIdx.x & 63;
    const unsigned int* a = reinterpret_cast<const unsigned int*>(zq + (size_t)pair * DIM);
    const unsigned int* b = reinterpret_cast<const unsigned int*>(zq + (size_t)(pair + NPAIR) * DIM);
    float s = 0.f;
#pragma unroll
    for (int i = 0; i < 3; ++i) {
        const unsigned int ua = a[lane + 64 * i];
        const unsigned int ub = b[lane + 64 * i];
        s += __builtin_amdgcn_cvt_f32_fp8(ua, 0) * __builtin_amdgcn_cvt_f32_fp8(ub, 0);
        s += __builtin_amdgcn_cvt_f32_fp8(ua, 1) * __builtin_amdgcn_cvt_f32_fp8(ub, 1);
        s += __builtin_amdgcn_cvt_f32_fp8(ua, 2) * __builtin_amdgcn_cvt_f32_fp8(ub, 2);
        s += __builtin_amdgcn_cvt_f32_fp8(ua, 3) * __builtin_amdgcn_cvt_f32_fp8(ub, 3);
    }
#pragma unroll
    for (int off = 32; off; off >>= 1) s += __shfl_xor(s, off);
    if (lane == 0) pos[pair] = s * INV_T;
}

// ---------------- main: R16 MX engine at 4 blocks/CU ------------------------
// Per iter: stage(next) first, 8 ds_read_b128 + 4 mfma_scale 32x32x64 fp8
// (scales=1.0), one vmcnt(0)+barrier. Epilogue per col-block (butterfly +
// atomics, R11-proven) instead of deferred rowacc: saves 32 VGPR ->
// ~116 unified regs -> 4 waves/SIMD -> 4 blocks/CU; grid 1024 = exactly
// 4/CU, no tail (R16 ran 3/CU + a 1/3-occupancy tail pass).
__global__ __launch_bounds__(256, 4) void klse(const unsigned char* __restrict__ zq,
                                               float* __restrict__ rowsum) {
    __shared__ __align__(16) unsigned char As[2][BM * KBLK];   // 2 x 8 KB
    __shared__ __align__(16) unsigned char Bs[2][BM * KBLK];   // 2 x 8 KB
    const int tid  = threadIdx.x;
    const int wave = tid >> 6;
    const int lane = tid & 63;
    const int wr = wave >> 1, wc = wave & 1;
    const int hi = lane >> 5, rlo = lane & 31;
    const int bi = blockIdx.x;
    const int rb = bi * BM;

    // ---- staging geometry (per-thread, loop-invariant) ----
    const int sr   = tid >> 2;                 // row within 64-row group
    const int soff = (((tid & 3) ^ ((sr >> 1) & 3)) << 4);  // swizzled src offset
    const size_t offA0 = (size_t)(rb + sr) * DIM + soff;
    const size_t offA1 = (size_t)(rb + 64 + sr) * DIM + soff;
    const size_t offB0 = (size_t)sr * DIM + soff;            // + c0*DIM at use
    const size_t offB1 = (size_t)(64 + sr) * DIM + soff;

    auto stage = [&](int c0, int koff, int buf) {
        __builtin_amdgcn_global_load_lds(
            (const AS1 unsigned int*)(zq + offA0 + koff),
            (AS3 unsigned int*)(&As[buf][tid * 16]), 16, 0, 0);
        __builtin_amdgcn_global_load_lds(
            (const AS1 unsigned int*)(zq + offA1 + koff),
            (AS3 unsigned int*)(&As[buf][4096 + tid * 16]), 16, 0, 0);
        __builtin_amdgcn_global_load_lds(
            (const AS1 unsigned int*)(zq + (size_t)c0 * DIM + offB0 + koff),
            (AS3 unsigned int*)(&Bs[buf][tid * 16]), 16, 0, 0);
        __builtin_amdgcn_global_load_lds(
            (const AS1 unsigned int*)(zq + (size_t)c0 * DIM + offB1 + koff),
            (AS3 unsigned int*)(&Bs[buf][4096 + tid * 16]), 16, 0, 0);
    };

    // ---- fragment-read geometry (constant per iter) ----
    const int sw  = (rlo >> 1) & 3;
    const int pg0 = ((2 * hi) ^ sw) << 4;      // first b128 (16B granule)
    const int pg1 = ((2 * hi + 1) ^ sw) << 4;  // second b128
    const int raA = (wr * 64 + rlo) * KBLK;
    const int raB = raA + 32 * KBLK;
    const int caA = (wc * 64 + rlo) * KBLK;
    const int caB = caA + 32 * KBLK;

    auto ldf = [&](const unsigned char* p) -> i32x8 {
        int4 u = *reinterpret_cast<const int4*>(p + pg0);
        int4 v = *reinterpret_cast<const int4*>(p + pg1);
        return i32x8{u.x, u.y, u.z, u.w, v.x, v.y, v.z, v.w};
    };

    f32x16 acc00 = {}, acc01 = {}, acc10 = {}, acc11 = {};
    const int row0b = rb + wr * 64 + 4 * hi;

    stage(blockIdx.y * CPB * BNB, 0, 0);
    asm volatile("s_waitcnt vmcnt(0)" ::: "memory");
    __builtin_amdgcn_s_barrier();

    int ct = 0, kt = 0;
    for (int it = 0; it < TOT; ++it) {
        const int cur = it & 1;
        int nct = ct, nkt = kt + 1;
        if (nkt == KITER) { nkt = 0; ++nct; }
        if (it + 1 < TOT)
            stage((blockIdx.y * CPB + nct) * BNB, nkt * KBLK, cur ^ 1);

        i32x8 a0 = ldf(&As[cur][raA]);
        i32x8 a1 = ldf(&As[cur][raB]);
        i32x8 b0 = ldf(&Bs[cur][caA]);
        i32x8 b1 = ldf(&Bs[cur][caB]);
        acc00 = __builtin_amdgcn_mfma_scale_f32_32x32x64_f8f6f4(a0, b0, acc00, 0, 0, 0, SC1, 0, SC1);
        acc01 = __builtin_amdgcn_mfma_scale_f32_32x32x64_f8f6f4(a0, b1, acc01, 0, 0, 0, SC1, 0, SC1);
        acc10 = __builtin_amdgcn_mfma_scale_f32_32x32x64_f8f6f4(a1, b0, acc10, 0, 0, 0, SC1, 0, SC1);
        acc11 = __builtin_amdgcn_mfma_scale_f32_32x32x64_f8f6f4(a1, b1, acc11, 0, 0, 0, SC1, 0, SC1);

        asm volatile("s_waitcnt vmcnt(0)" ::: "memory");  // next buffer landed
        __builtin_amdgcn_s_barrier();                     // all reads of buf done

        if (kt == KITER - 1) {
            // ---------- epilogue for col-block ct: exp, mask, reduce --------
            const int cblk = blockIdx.y * CPB + ct;
            const bool on_diag = (cblk == bi);
            const int colg = cblk * BNB + wc * 64 + rlo;
            float ps0[16], ps1[16];
#pragma unroll
            for (int r = 0; r < 16; ++r) {
                const int rg0 = row0b + (r & 3) + 8 * (r >> 2);
                float e00 = __expf((acc00[r] - 1.0f) * INV_T);
                float e01 = __expf((acc01[r] - 1.0f) * INV_T);
                float e10 = __expf((acc10[r] - 1.0f) * INV_T);
                float e11 = __expf((acc11[r] - 1.0f) * INV_T);
                if (on_diag) {
                    if (rg0 == colg)           e00 = 0.f;
                    if (rg0 == colg + 32)      e01 = 0.f;
                    if (rg0 + 32 == colg)      e10 = 0.f;
                    if (rg0 + 32 == colg + 32) e11 = 0.f;
                }
                ps0[r] = e00 + e01;
                ps1[r] = e10 + e11;
            }
#pragma unroll
            for (int r = 0; r < 16; ++r) {
#pragma unroll
                for (int m = 1; m < 32; m <<= 1) {
                    ps0[r] += __shfl_xor(ps0[r], m);
                    ps1[r] += __shfl_xor(ps1[r], m);
                }
            }
            if (rlo == 0) {
#pragma unroll
                for (int r = 0; r < 16; ++r) {
                    const int rg0 = row0b + (r & 3) + 8 * (r >> 2);
                    atomicAdd(&rowsum[rg0], ps0[r]);
                    atomicAdd(&rowsum[rg0 + 32], ps1[r]);
                }
            }
            acc00 = f32x16{}; acc01 = f32x16{};
            acc10 = f32x16{}; acc11 = f32x16{};
        }
        ct = nct; kt = nkt;
    }
}

// ---------------- final: loss = mean(M + log S_i - pos) ---------------------
__global__ void kfinal(const float* __restrict__ rowsum, const float* __restrict__ pos,
                       float* __restrict__ out) {
    __shared__ float red[8];
    const int tid = threadIdx.x;
    float s = 0.f;
    for (int i = tid; i < N2; i += 512) {
        const int p = (i < NPAIR) ? i : i - NPAIR;
        s += INV_T + __logf(rowsum[i]) - pos[p];
    }
#pragma unroll
    for (int off = 32; off; off >>= 1) s += __shfl_xor(s, off);
    if ((tid & 63) == 0) red[tid >> 6] = s;
    __syncthreads();
    if (tid == 0) {
        float t = 0.f;
#pragma unroll
        for (int w = 0; w < 8; ++w) t += red[w];
        out[0] = t / (float)N2;
    }
}

extern "C" void kernel_launch(void* const* d_in, const int* in_sizes, int n_in,
                              void* d_out, int out_size, void* d_ws, size_t ws_size,
                              hipStream_t stream) {
    const float* z1 = (const float*)d_in[0];
    const float* z2 = (const float*)d_in[1];
    unsigned char* zq = (unsigned char*)d_ws;                         // 8192*768 fp8
    float* rowsum = (float*)((char*)d_ws + (size_t)N2 * DIM);         // 8192 f32
    float* pos = rowsum + N2;                                         // 4096 f32
    float* out = (float*)d_out;

    hipLaunchKernelGGL(knorm, dim3(N2 / 4), dim3(256), 0, stream, z1, z2, zq);
    hipLaunchKernelGGL(kpos, dim3(NPAIR / 4), dim3(256), 0, stream, zq, pos);
    hipMemsetAsync(rowsum, 0, N2 * sizeof(float), stream);
    hipLaunchKernelGGL(klse, dim3(NBI, NSTRIP), dim3(256), 0, stream, zq, rowsum);
    hipLaunchKernelGGL(kfinal, dim3(1), dim3(512), 0, stream, rowsum, pos, out);
}

// Round 20
// 101.429 us; speedup vs baseline: 1.0892x; 1.0892x over previous
//
#include <hip/hip_runtime.h>
#include <hip/hip_bf16.h>

#define NPAIR 4096
#define DIM   768            // fp8: 768 bytes per row
#define N2    8192
#define BM    128            // block rows (4 waves as 2x2, each 64x64)
#define BNB   128            // block cols per col-block
#define KBLK  64             // K tile bytes; dbuf = 32KB total
#define KITER (DIM / KBLK)   // 12
#define NSTRIP 16            // grid.y
#define CPB   ((N2 / BNB) / NSTRIP)    // 4 col-blocks per strip
#define NBI   (N2 / BM)      // 64
#define TOT   (CPB * KITER)  // 48 K-tile iterations per block
#define SC1   0x7F7F7F7F     // packed E8M0 scales: all 1.0

constexpr float INV_T = 1.0f / 0.07f;  // also the fixed softmax max M

typedef float f32x16 __attribute__((ext_vector_type(16)));
typedef int   i32x8  __attribute__((ext_vector_type(8)));
#define AS1 __attribute__((address_space(1)))
#define AS3 __attribute__((address_space(3)))

// -------- normalize: one wave per row, fp32 in -> fp8 e4m3 out; also zeroes
// -------- rowsum (blocks 0..31), replacing the separate memset -------------
__global__ void knorm(const float* __restrict__ z1, const float* __restrict__ z2,
                      unsigned char* __restrict__ zq, float* __restrict__ rowsum) {
    if (blockIdx.x < 32) rowsum[blockIdx.x * 256 + threadIdx.x] = 0.f;
    const int row  = blockIdx.x * 4 + (threadIdx.x >> 6);
    const int lane = threadIdx.x & 63;
    const float* src = (row < NPAIR) ? (z1 + (size_t)row * DIM)
                                     : (z2 + (size_t)(row - NPAIR) * DIM);
    float4 v[3];
    float ss = 0.f;
#pragma unroll
    for (int i = 0; i < 3; ++i) {
        v[i] = reinterpret_cast<const float4*>(src)[lane + 64 * i];
        ss += v[i].x * v[i].x + v[i].y * v[i].y + v[i].z * v[i].z + v[i].w * v[i].w;
    }
#pragma unroll
    for (int off = 32; off; off >>= 1) ss += __shfl_xor(ss, off);
    const float scale = 1.0f / fmaxf(sqrtf(ss), 1e-12f);
    unsigned int* dst = reinterpret_cast<unsigned int*>(zq + (size_t)row * DIM);
#pragma unroll
    for (int i = 0; i < 3; ++i) {
        unsigned int u = 0;
        u = __builtin_amdgcn_cvt_pk_fp8_f32(v[i].x * scale, v[i].y * scale, u, false);
        u = __builtin_amdgcn_cvt_pk_fp8_f32(v[i].z * scale, v[i].w * scale, u, true);
        dst[lane + 64 * i] = u;
    }
}

// ---------------- main: R16 MX engine + fused pos extraction ----------------
// Per iter: stage(next) first, 8 ds_read_b128 + 4 mfma_scale 32x32x64 fp8
// (scales=1.0), one vmcnt(0)+barrier. Deferred epilogue (rowacc in regs, one
// butterfly per block). pos[i] = sim[i][i+NPAIR]*INV_T harvested in the
// epilogue (each sim entry computed exactly once) -- kpos kernel removed.
__global__ __launch_bounds__(256, 3) void klse(const unsigned char* __restrict__ zq,
                                               float* __restrict__ rowsum,
                                               float* __restrict__ pos) {
    __shared__ __align__(16) unsigned char As[2][BM * KBLK];   // 2 x 8 KB
    __shared__ __align__(16) unsigned char Bs[2][BM * KBLK];   // 2 x 8 KB
    const int tid  = threadIdx.x;
    const int wave = tid >> 6;
    const int lane = tid & 63;
    const int wr = wave >> 1, wc = wave & 1;
    const int hi = lane >> 5, rlo = lane & 31;
    const int bi = blockIdx.x;
    const int rb = bi * BM;

    // ---- staging geometry (per-thread, loop-invariant) ----
    const int sr   = tid >> 2;                 // row within 64-row group
    const int soff = (((tid & 3) ^ ((sr >> 1) & 3)) << 4);  // swizzled src offset
    const size_t offA0 = (size_t)(rb + sr) * DIM + soff;
    const size_t offA1 = (size_t)(rb + 64 + sr) * DIM + soff;
    const size_t offB0 = (size_t)sr * DIM + soff;            // + c0*DIM at use
    const size_t offB1 = (size_t)(64 + sr) * DIM + soff;

    auto stage = [&](int c0, int koff, int buf) {
        __builtin_amdgcn_global_load_lds(
            (const AS1 unsigned int*)(zq + offA0 + koff),
            (AS3 unsigned int*)(&As[buf][tid * 16]), 16, 0, 0);
        __builtin_amdgcn_global_load_lds(
            (const AS1 unsigned int*)(zq + offA1 + koff),
            (AS3 unsigned int*)(&As[buf][4096 + tid * 16]), 16, 0, 0);
        __builtin_amdgcn_global_load_lds(
            (const AS1 unsigned int*)(zq + (size_t)c0 * DIM + offB0 + koff),
            (AS3 unsigned int*)(&Bs[buf][tid * 16]), 16, 0, 0);
        __builtin_amdgcn_global_load_lds(
            (const AS1 unsigned int*)(zq + (size_t)c0 * DIM + offB1 + koff),
            (AS3 unsigned int*)(&Bs[buf][4096 + tid * 16]), 16, 0, 0);
    };

    // ---- fragment-read geometry (constant per iter) ----
    const int sw  = (rlo >> 1) & 3;
    const int pg0 = ((2 * hi) ^ sw) << 4;      // first b128 (16B granule)
    const int pg1 = ((2 * hi + 1) ^ sw) << 4;  // second b128
    const int raA = (wr * 64 + rlo) * KBLK;
    const int raB = raA + 32 * KBLK;
    const int caA = (wc * 64 + rlo) * KBLK;
    const int caB = caA + 32 * KBLK;

    auto ldf = [&](const unsigned char* p) -> i32x8 {
        int4 u = *reinterpret_cast<const int4*>(p + pg0);
        int4 v = *reinterpret_cast<const int4*>(p + pg1);
        return i32x8{u.x, u.y, u.z, u.w, v.x, v.y, v.z, v.w};
    };

    f32x16 acc00 = {}, acc01 = {}, acc10 = {}, acc11 = {};
    float rowacc0[16], rowacc1[16];
#pragma unroll
    for (int r = 0; r < 16; ++r) { rowacc0[r] = 0.f; rowacc1[r] = 0.f; }
    const int row0b = rb + wr * 64 + 4 * hi;

    stage(blockIdx.y * CPB * BNB, 0, 0);
    asm volatile("s_waitcnt vmcnt(0)" ::: "memory");
    __builtin_amdgcn_s_barrier();

    int ct = 0, kt = 0;
    for (int it = 0; it < TOT; ++it) {
        const int cur = it & 1;
        int nct = ct, nkt = kt + 1;
        if (nkt == KITER) { nkt = 0; ++nct; }
        if (it + 1 < TOT)
            stage((blockIdx.y * CPB + nct) * BNB, nkt * KBLK, cur ^ 1);

        i32x8 a0 = ldf(&As[cur][raA]);
        i32x8 a1 = ldf(&As[cur][raB]);
        i32x8 b0 = ldf(&Bs[cur][caA]);
        i32x8 b1 = ldf(&Bs[cur][caB]);
        acc00 = __builtin_amdgcn_mfma_scale_f32_32x32x64_f8f6f4(a0, b0, acc00, 0, 0, 0, SC1, 0, SC1);
        acc01 = __builtin_amdgcn_mfma_scale_f32_32x32x64_f8f6f4(a0, b1, acc01, 0, 0, 0, SC1, 0, SC1);
        acc10 = __builtin_amdgcn_mfma_scale_f32_32x32x64_f8f6f4(a1, b0, acc10, 0, 0, 0, SC1, 0, SC1);
        acc11 = __builtin_amdgcn_mfma_scale_f32_32x32x64_f8f6f4(a1, b1, acc11, 0, 0, 0, SC1, 0, SC1);

        asm volatile("s_waitcnt vmcnt(0)" ::: "memory");  // next buffer landed
        __builtin_amdgcn_s_barrier();                     // all reads of buf done

        if (kt == KITER - 1) {
            // exp + mask + per-lane accumulate; harvest pos on the pair band
            const int cblk = blockIdx.y * CPB + ct;
            const bool on_diag = (cblk == bi);
            const bool on_pos  = (cblk == bi + NPAIR / BNB);  // col == row + 4096 band
            const int colg = cblk * BNB + wc * 64 + rlo;
#pragma unroll
            for (int r = 0; r < 16; ++r) {
                const int rg0 = row0b + (r & 3) + 8 * (r >> 2);
                float e00 = __expf((acc00[r] - 1.0f) * INV_T);
                float e01 = __expf((acc01[r] - 1.0f) * INV_T);
                float e10 = __expf((acc10[r] - 1.0f) * INV_T);
                float e11 = __expf((acc11[r] - 1.0f) * INV_T);
                if (on_diag) {
                    if (rg0 == colg)           e00 = 0.f;
                    if (rg0 == colg + 32)      e01 = 0.f;
                    if (rg0 + 32 == colg)      e10 = 0.f;
                    if (rg0 + 32 == colg + 32) e11 = 0.f;
                }
                if (on_pos) {
                    if (colg == rg0 + NPAIR)           pos[rg0]      = acc00[r] * INV_T;
                    if (colg + 32 == rg0 + NPAIR)      pos[rg0]      = acc01[r] * INV_T;
                    if (colg == rg0 + 32 + NPAIR)      pos[rg0 + 32] = acc10[r] * INV_T;
                    if (colg + 32 == rg0 + 32 + NPAIR) pos[rg0 + 32] = acc11[r] * INV_T;
                }
                rowacc0[r] += e00 + e01;
                rowacc1[r] += e10 + e11;
            }
            acc00 = f32x16{}; acc01 = f32x16{};
            acc10 = f32x16{}; acc11 = f32x16{};
        }
        ct = nct; kt = nkt;
    }

    // block end: ONE butterfly over 32 col-lanes + atomics
#pragma unroll
    for (int r = 0; r < 16; ++r) {
#pragma unroll
        for (int m = 1; m < 32; m <<= 1) {
            rowacc0[r] += __shfl_xor(rowacc0[r], m);
            rowacc1[r] += __shfl_xor(rowacc1[r], m);
        }
    }
    if (rlo == 0) {
#pragma unroll
        for (int r = 0; r < 16; ++r) {
            const int rg0 = row0b + (r & 3) + 8 * (r >> 2);
            atomicAdd(&rowsum[rg0], rowacc0[r]);
            atomicAdd(&rowsum[rg0 + 32], rowacc1[r]);
        }
    }
}

// ---------------- final: loss = mean(M + log S_i - pos) ---------------------
__global__ void kfinal(const float* __restrict__ rowsum, const float* __restrict__ pos,
                       float* __restrict__ out) {
    __shared__ float red[8];
    const int tid = threadIdx.x;
    float s = 0.f;
    for (int i = tid; i < N2; i += 512) {
        const int p = (i < NPAIR) ? i : i - NPAIR;
        s += INV_T + __logf(rowsum[i]) - pos[p];
    }
#pragma unroll
    for (int off = 32; off; off >>= 1) s += __shfl_xor(s, off);
    if ((tid & 63) == 0) red[tid >> 6] = s;
    __syncthreads();
    if (tid == 0) {
        float t = 0.f;
#pragma unroll
        for (int w = 0; w < 8; ++w) t += red[w];
        out[0] = t / (float)N2;
    }
}

extern "C" void kernel_launch(void* const* d_in, const int* in_sizes, int n_in,
                              void* d_out, int out_size, void* d_ws, size_t ws_size,
                              hipStream_t stream) {
    const float* z1 = (const float*)d_in[0];
    const float* z2 = (const float*)d_in[1];
    unsigned char* zq = (unsigned char*)d_ws;                         // 8192*768 fp8
    float* rowsum = (float*)((char*)d_ws + (size_t)N2 * DIM);         // 8192 f32
    float* pos = rowsum + N2;                                         // 4096 f32
    float* out = (float*)d_out;

    hipLaunchKernelGGL(knorm, dim3(N2 / 4), dim3(256), 0, stream, z1, z2, zq, rowsum);
    hipLaunchKernelGGL(klse, dim3(NBI, NSTRIP), dim3(256), 0, stream, zq, rowsum, pos);
    hipLaunchKernelGGL(kfinal, dim3(1), dim3(512), 0, stream, rowsum, pos, out);
}

// Round 21
// 88.433 us; speedup vs baseline: 1.2493x; 1.1470x over previous
//
#include <hip/hip_runtime.h>
#include <hip/hip_bf16.h>

#define NPAIR 4096
#define DIM   768            // fp8: 768 bytes per row
#define N2    8192
#define BM    128            // block rows (4 waves as 2x2, each 64x64)
#define BNB   128            // block cols per col-block
#define KBLK  128            // K tile bytes; A,B tiles 16KB; dbuf = 64KB
#define KITER (DIM / KBLK)   // 6
#define NSTRIP 16            // grid.y
#define CPB   ((N2 / BNB) / NSTRIP)    // 4 col-blocks per strip
#define NBI   (N2 / BM)      // 64
#define TOT   (CPB * KITER)  // 24 K-tile iterations per block
#define SC1   0x7F7F7F7F     // packed E8M0 scales: all 1.0

constexpr float INV_T = 1.0f / 0.07f;  // also the fixed softmax max M

typedef float f32x16 __attribute__((ext_vector_type(16)));
typedef int   i32x8  __attribute__((ext_vector_type(8)));
#define AS1 __attribute__((address_space(1)))
#define AS3 __attribute__((address_space(3)))

// -------- normalize: one wave per row, fp32 in -> fp8 e4m3 out; also zeroes
// -------- rowsum (blocks 0..31), replacing the separate memset -------------
__global__ void knorm(const float* __restrict__ z1, const float* __restrict__ z2,
                      unsigned char* __restrict__ zq, float* __restrict__ rowsum) {
    if (blockIdx.x < 32) rowsum[blockIdx.x * 256 + threadIdx.x] = 0.f;
    const int row  = blockIdx.x * 4 + (threadIdx.x >> 6);
    const int lane = threadIdx.x & 63;
    const float* src = (row < NPAIR) ? (z1 + (size_t)row * DIM)
                                     : (z2 + (size_t)(row - NPAIR) * DIM);
    float4 v[3];
    float ss = 0.f;
#pragma unroll
    for (int i = 0; i < 3; ++i) {
        v[i] = reinterpret_cast<const float4*>(src)[lane + 64 * i];
        ss += v[i].x * v[i].x + v[i].y * v[i].y + v[i].z * v[i].z + v[i].w * v[i].w;
    }
#pragma unroll
    for (int off = 32; off; off >>= 1) ss += __shfl_xor(ss, off);
    const float scale = 1.0f / fmaxf(sqrtf(ss), 1e-12f);
    unsigned int* dst = reinterpret_cast<unsigned int*>(zq + (size_t)row * DIM);
#pragma unroll
    for (int i = 0; i < 3; ++i) {
        unsigned int u = 0;
        u = __builtin_amdgcn_cvt_pk_fp8_f32(v[i].x * scale, v[i].y * scale, u, false);
        u = __builtin_amdgcn_cvt_pk_fp8_f32(v[i].z * scale, v[i].w * scale, u, true);
        dst[lane + 64 * i] = u;
    }
}

// ---------------- main: R19 MX engine with KBLK=128 (fat iterations) --------
// Per iter: stage(next, 8 gload_lds) first, then 16 ds_read_b128 +
// 8 mfma_scale 32x32x64 fp8 (scales=1.0), one vmcnt(0)+barrier pair.
// 24 iters/block (was 48): barrier/sync events halve at constant work.
// 8-granule swizzle slot = k ^ (row&7) (4-way floor). 64KB dbuf -> 2
// blocks/CU, grid 1024 = exactly 2 passes. pos fused, rowacc deferred.
__global__ __launch_bounds__(256, 2) void klse(const unsigned char* __restrict__ zq,
                                               float* __restrict__ rowsum,
                                               float* __restrict__ pos) {
    __shared__ __align__(16) unsigned char As[2][BM * KBLK];   // 2 x 16 KB
    __shared__ __align__(16) unsigned char Bs[2][BM * KBLK];   // 2 x 16 KB
    const int tid  = threadIdx.x;
    const int wave = tid >> 6;
    const int lane = tid & 63;
    const int wr = wave >> 1, wc = wave & 1;
    const int hi = lane >> 5, rlo = lane & 31;
    const int bi = blockIdx.x;
    const int rb = bi * BM;

    // ---- staging geometry (per-thread, loop-invariant) ----
    const int sr   = tid >> 3;                 // row within 32-row group
    const int soff = (((tid & 7) ^ (sr & 7)) << 4);          // swizzled src offset
    size_t offA[4], offB[4];
#pragma unroll
    for (int i = 0; i < 4; ++i) {
        offA[i] = (size_t)(rb + i * 32 + sr) * DIM + soff;
        offB[i] = (size_t)(i * 32 + sr) * DIM + soff;        // + c0*DIM at use
    }

    auto stage = [&](int c0, int koff, int buf) {
#pragma unroll
        for (int i = 0; i < 4; ++i) {
            __builtin_amdgcn_global_load_lds(
                (const AS1 unsigned int*)(zq + offA[i] + koff),
                (AS3 unsigned int*)(&As[buf][(i * 256 + tid) * 16]), 16, 0, 0);
            __builtin_amdgcn_global_load_lds(
                (const AS1 unsigned int*)(zq + (size_t)c0 * DIM + offB[i] + koff),
                (AS3 unsigned int*)(&Bs[buf][(i * 256 + tid) * 16]), 16, 0, 0);
        }
    };

    // ---- fragment-read geometry (constant per iter) ----
    const int sw = rlo & 7;
    int pg[2][2];                              // [K-step][granule pair]
#pragma unroll
    for (int s = 0; s < 2; ++s) {
        pg[s][0] = ((4 * s + 2 * hi) ^ sw) << 4;
        pg[s][1] = ((4 * s + 2 * hi + 1) ^ sw) << 4;
    }
    const int raA = (wr * 64 + rlo) * KBLK;
    const int raB = raA + 32 * KBLK;
    const int caA = (wc * 64 + rlo) * KBLK;
    const int caB = caA + 32 * KBLK;

    f32x16 acc00 = {}, acc01 = {}, acc10 = {}, acc11 = {};
    float rowacc0[16], rowacc1[16];
#pragma unroll
    for (int r = 0; r < 16; ++r) { rowacc0[r] = 0.f; rowacc1[r] = 0.f; }
    const int row0b = rb + wr * 64 + 4 * hi;

    stage(blockIdx.y * CPB * BNB, 0, 0);
    asm volatile("s_waitcnt vmcnt(0)" ::: "memory");
    __builtin_amdgcn_s_barrier();

    int ct = 0, kt = 0;
    for (int it = 0; it < TOT; ++it) {
        const int cur = it & 1;
        int nct = ct, nkt = kt + 1;
        if (nkt == KITER) { nkt = 0; ++nct; }
        if (it + 1 < TOT)
            stage((blockIdx.y * CPB + nct) * BNB, nkt * KBLK, cur ^ 1);

#pragma unroll
        for (int s = 0; s < 2; ++s) {
            auto ldf = [&](const unsigned char* p) -> i32x8 {
                int4 u = *reinterpret_cast<const int4*>(p + pg[s][0]);
                int4 v = *reinterpret_cast<const int4*>(p + pg[s][1]);
                return i32x8{u.x, u.y, u.z, u.w, v.x, v.y, v.z, v.w};
            };
            i32x8 a0 = ldf(&As[cur][raA]);
            i32x8 a1 = ldf(&As[cur][raB]);
            i32x8 b0 = ldf(&Bs[cur][caA]);
            i32x8 b1 = ldf(&Bs[cur][caB]);
            acc00 = __builtin_amdgcn_mfma_scale_f32_32x32x64_f8f6f4(a0, b0, acc00, 0, 0, 0, SC1, 0, SC1);
            acc01 = __builtin_amdgcn_mfma_scale_f32_32x32x64_f8f6f4(a0, b1, acc01, 0, 0, 0, SC1, 0, SC1);
            acc10 = __builtin_amdgcn_mfma_scale_f32_32x32x64_f8f6f4(a1, b0, acc10, 0, 0, 0, SC1, 0, SC1);
            acc11 = __builtin_amdgcn_mfma_scale_f32_32x32x64_f8f6f4(a1, b1, acc11, 0, 0, 0, SC1, 0, SC1);
        }

        asm volatile("s_waitcnt vmcnt(0)" ::: "memory");  // next buffer landed
        __builtin_amdgcn_s_barrier();                     // all reads of buf done

        if (kt == KITER - 1) {
            // exp + mask + per-lane accumulate; harvest pos on the pair band
            const int cblk = blockIdx.y * CPB + ct;
            const bool on_diag = (cblk == bi);
            const bool on_pos  = (cblk == bi + NPAIR / BNB);  // col == row + 4096 band
            const int colg = cblk * BNB + wc * 64 + rlo;
#pragma unroll
            for (int r = 0; r < 16; ++r) {
                const int rg0 = row0b + (r & 3) + 8 * (r >> 2);
                float e00 = __expf((acc00[r] - 1.0f) * INV_T);
                float e01 = __expf((acc01[r] - 1.0f) * INV_T);
                float e10 = __expf((acc10[r] - 1.0f) * INV_T);
                float e11 = __expf((acc11[r] - 1.0f) * INV_T);
                if (on_diag) {
                    if (rg0 == colg)           e00 = 0.f;
                    if (rg0 == colg + 32)      e01 = 0.f;
                    if (rg0 + 32 == colg)      e10 = 0.f;
                    if (rg0 + 32 == colg + 32) e11 = 0.f;
                }
                if (on_pos) {
                    if (colg == rg0 + NPAIR)           pos[rg0]      = acc00[r] * INV_T;
                    if (colg + 32 == rg0 + NPAIR)      pos[rg0]      = acc01[r] * INV_T;
                    if (colg == rg0 + 32 + NPAIR)      pos[rg0 + 32] = acc10[r] * INV_T;
                    if (colg + 32 == rg0 + 32 + NPAIR) pos[rg0 + 32] = acc11[r] * INV_T;
                }
                rowacc0[r] += e00 + e01;
                rowacc1[r] += e10 + e11;
            }
            acc00 = f32x16{}; acc01 = f32x16{};
            acc10 = f32x16{}; acc11 = f32x16{};
        }
        ct = nct; kt = nkt;
    }

    // block end: ONE butterfly over 32 col-lanes + atomics
#pragma unroll
    for (int r = 0; r < 16; ++r) {
#pragma unroll
        for (int m = 1; m < 32; m <<= 1) {
            rowacc0[r] += __shfl_xor(rowacc0[r], m);
            rowacc1[r] += __shfl_xor(rowacc1[r], m);
        }
    }
    if (rlo == 0) {
#pragma unroll
        for (int r = 0; r < 16; ++r) {
            const int rg0 = row0b + (r & 3) + 8 * (r >> 2);
            atomicAdd(&rowsum[rg0], rowacc0[r]);
            atomicAdd(&rowsum[rg0 + 32], rowacc1[r]);
        }
    }
}

// ---------------- final: loss = mean(M + log S_i - pos) ---------------------
__global__ void kfinal(const float* __restrict__ rowsum, const float* __restrict__ pos,
                       float* __restrict__ out) {
    __shared__ float red[8];
    const int tid = threadIdx.x;
    float s = 0.f;
    for (int i = tid; i < N2; i += 512) {
        const int p = (i < NPAIR) ? i : i - NPAIR;
        s += INV_T + __logf(rowsum[i]) - pos[p];
    }
#pragma unroll
    for (int off = 32; off; off >>= 1) s += __shfl_xor(s, off);
    if ((tid & 63) == 0) red[tid >> 6] = s;
    __syncthreads();
    if (tid == 0) {
        float t = 0.f;
#pragma unroll
        for (int w = 0; w < 8; ++w) t += red[w];
        out[0] = t / (float)N2;
    }
}

extern "C" void kernel_launch(void* const* d_in, const int* in_sizes, int n_in,
                              void* d_out, int out_size, void* d_ws, size_t ws_size,
                              hipStream_t stream) {
    const float* z1 = (const float*)d_in[0];
    const float* z2 = (const float*)d_in[1];
    unsigned char* zq = (unsigned char*)d_ws;                         // 8192*768 fp8
    float* rowsum = (float*)((char*)d_ws + (size_t)N2 * DIM);         // 8192 f32
    float* pos = rowsum + N2;                                         // 4096 f32
    float* out = (float*)d_out;

    hipLaunchKernelGGL(knorm, dim3(N2 / 4), dim3(256), 0, stream, z1, z2, zq, rowsum);
    hipLaunchKernelGGL(klse, dim3(NBI, NSTRIP), dim3(256), 0, stream, zq, rowsum, pos);
    hipLaunchKernelGGL(kfinal, dim3(1), dim3(512), 0, stream, rowsum, pos, out);
}